// Round 3
// baseline (475.825 us; speedup 1.0000x reference)
//
#include <hip/hip_runtime.h>
#include <hip/hip_bf16.h>
#include <stdint.h>
#include <stddef.h>

#define B_ 4
#define N_ 1024
#define C_ 384
#define H_ 6
#define D_ 64
#define TC_ 1152          // 3*C
#define BHNN_ 25165824    // B*H*N*N
#define SCALE 0.125f
#define LOG2E 1.4426950408889634f
#define LN2 0.6931471805599453f

typedef __hip_bfloat16 bf16;
typedef __attribute__((ext_vector_type(2))) float f32x2;
typedef __attribute__((ext_vector_type(4))) float f32x4;
typedef __attribute__((ext_vector_type(8))) short short8;

union f4u { f32x4 v4; f32x2 v2[2]; };

__device__ __forceinline__ short f2bs(float x){
  bf16 b = __float2bfloat16(x);
  return *reinterpret_cast<short*>(&b);
}

// packed dual-FMA with src0 broadcast via op_sel (numerically = v_fma_f32 on both halves)
__device__ __forceinline__ void pk_fma_ll(f32x2& c, f32x2 a, f32x2 b){
  asm("v_pk_fma_f32 %0, %1, %2, %0 op_sel:[0,0,0] op_sel_hi:[0,1,1]" : "+v"(c) : "v"(a), "v"(b));
}
__device__ __forceinline__ void pk_fma_hh(f32x2& c, f32x2 a, f32x2 b){
  asm("v_pk_fma_f32 %0, %1, %2, %0 op_sel:[1,0,0] op_sel_hi:[1,1,1]" : "+v"(c) : "v"(a), "v"(b));
}

// ---------------- Threefry-2x32 (matches jax._src.prng) ----------------
#define TFR(x0,x1,r) { x0 += x1; x1 = ((x1)<<(r))|((x1)>>(32-(r))); x1 ^= x0; }

__host__ __device__ __forceinline__ void tf2x32(uint32_t k0, uint32_t k1,
                                                uint32_t& x0, uint32_t& x1){
  uint32_t k2 = k0 ^ k1 ^ 0x1BD11BDAu;
  x0 += k0; x1 += k1;
  TFR(x0,x1,13) TFR(x0,x1,15) TFR(x0,x1,26) TFR(x0,x1,6)
  x0 += k1; x1 += k2 + 1u;
  TFR(x0,x1,17) TFR(x0,x1,29) TFR(x0,x1,16) TFR(x0,x1,24)
  x0 += k2; x1 += k0 + 2u;
  TFR(x0,x1,13) TFR(x0,x1,15) TFR(x0,x1,26) TFR(x0,x1,6)
  x0 += k0; x1 += k1 + 3u;
  TFR(x0,x1,17) TFR(x0,x1,29) TFR(x0,x1,16) TFR(x0,x1,24)
  x0 += k1; x1 += k2 + 4u;
  TFR(x0,x1,13) TFR(x0,x1,15) TFR(x0,x1,26) TFR(x0,x1,6)
  x0 += k2; x1 += k0 + 5u;
}

__device__ __forceinline__ uint32_t rotl32(uint32_t x, uint32_t r){
#if __has_builtin(__builtin_amdgcn_alignbit)
  return __builtin_amdgcn_alignbit(x, x, 32u - r);
#else
  return (x << r) | (x >> (32u - r));
#endif
}

// dual-stream threefry: uniforms for BOTH gumbel keys at counter (0, j), 2-way ILP
__device__ __forceinline__ void tf_dual(uint32_t j,
    uint32_t ak0, uint32_t ak1, uint32_t ak2,
    uint32_t bk0, uint32_t bk1, uint32_t bk2,
    float& fA, float& fB){
  uint32_t x0 = ak0, x1 = j + ak1;
  uint32_t y0 = bk0, y1 = j + bk1;
  #define DTFR(r) { x0 += x1; y0 += y1;               \
                    x1 = rotl32(x1,(r)); y1 = rotl32(y1,(r)); \
                    x1 ^= x0; y1 ^= y0; }
  DTFR(13) DTFR(15) DTFR(26) DTFR(6)
  x0 += ak1; x1 += ak2 + 1u;  y0 += bk1; y1 += bk2 + 1u;
  DTFR(17) DTFR(29) DTFR(16) DTFR(24)
  x0 += ak2; x1 += ak0 + 2u;  y0 += bk2; y1 += bk0 + 2u;
  DTFR(13) DTFR(15) DTFR(26) DTFR(6)
  x0 += ak0; x1 += ak1 + 3u;  y0 += bk0; y1 += bk1 + 3u;
  DTFR(17) DTFR(29) DTFR(16) DTFR(24)
  x0 += ak1; x1 += ak2 + 4u;  y0 += bk1; y1 += bk2 + 4u;
  DTFR(13) DTFR(15) DTFR(26) DTFR(6)
  x0 += ak2; x1 += ak0 + 5u;  y0 += bk2; y1 += bk0 + 5u;
  #undef DTFR
  uint32_t bitsA = x0 ^ x1;
  uint32_t bitsB = y0 ^ y1;
  fA = fmaxf(__uint_as_float((bitsA >> 9) | 0x3F800000u) - 1.0f, 1.1754943508222875e-38f);
  fB = fmaxf(__uint_as_float((bitsB >> 9) | 0x3F800000u) - 1.0f, 1.1754943508222875e-38f);
}

// ---------------- Kernel A: qkv = x @ qkv_w + b -> qb, kb (B,H,N,D bf16), vT (B,H,D,N bf16)
// inner loop: 2x ds_read_b128 + 8x v_pk_fma_f32 (op_sel broadcast) = 32 FLOP / 10 slots
__global__ __launch_bounds__(256) void k_qkv(const float* __restrict__ x,
                                             const float* __restrict__ w,
                                             const float* __restrict__ bias,
                                             bf16* __restrict__ qb,
                                             bf16* __restrict__ kb,
                                             bf16* __restrict__ vTb){
  __shared__ __align__(16) float As[16][68];   // [k][m]
  __shared__ __align__(16) float Bs[16][68];   // [k][n]
  const int t  = threadIdx.x;
  const int tx = t & 15, ty = t >> 4;
  const int m0 = blockIdx.x * 64, n0 = blockIdx.y * 64;
  // staging maps (vectorized)
  const int am = t >> 2,        ak = (t & 3) * 4;   // A: f32x4 along k (transposed LDS write)
  const int bn = (t & 15) * 4,  bk = t >> 4;        // B: f32x4 along n (b128 LDS write)
  f32x2 c[4][2] = {};
  for (int k0 = 0; k0 < C_; k0 += 16){
    f32x4 av = *(const f32x4*)&x[(size_t)(m0+am)*C_ + k0 + ak];
    f32x4 bv = *(const f32x4*)&w[(size_t)(k0+bk)*TC_ + n0 + bn];
    __syncthreads();                 // previous iteration's readers done
    As[ak+0][am] = av[0]; As[ak+1][am] = av[1];
    As[ak+2][am] = av[2]; As[ak+3][am] = av[3];
    *(f32x4*)&Bs[bk][bn] = bv;
    __syncthreads();
    #pragma unroll
    for (int k = 0; k < 16; k++){
      f4u a, b;
      a.v4 = *(const f32x4*)&As[k][ty*4];
      b.v4 = *(const f32x4*)&Bs[k][tx*4];
      pk_fma_ll(c[0][0], a.v2[0], b.v2[0]); pk_fma_ll(c[0][1], a.v2[0], b.v2[1]);
      pk_fma_hh(c[1][0], a.v2[0], b.v2[0]); pk_fma_hh(c[1][1], a.v2[0], b.v2[1]);
      pk_fma_ll(c[2][0], a.v2[1], b.v2[0]); pk_fma_ll(c[2][1], a.v2[1], b.v2[1]);
      pk_fma_hh(c[3][0], a.v2[1], b.v2[0]); pk_fma_hh(c[3][1], a.v2[1], b.v2[1]);
    }
  }
  #pragma unroll
  for (int i = 0; i < 4; i++){
    int mg = m0 + ty*4 + i;
    int bb = mg >> 10, nn = mg & 1023;
    #pragma unroll
    for (int jp = 0; jp < 2; jp++){
      #pragma unroll
      for (int sub = 0; sub < 2; sub++){
        int jg = n0 + tx*4 + jp*2 + sub;
        int t3 = jg / C_;
        int rem = jg - t3*C_;
        int h = rem >> 6, d = rem & 63;
        bf16 val = __float2bfloat16(c[i][jp][sub] + bias[jg]);
        if (t3 == 0)      qb[((size_t)(bb*H_ + h)*N_ + nn)*D_ + d] = val;
        else if (t3 == 1) kb[((size_t)(bb*H_ + h)*N_ + nn)*D_ + d] = val;
        else              vTb[((size_t)(bb*H_ + h)*D_ + d)*N_ + nn] = val;
      }
    }
  }
}

// ---------------- Kernel B (MFMA): scores[bh][n][m] = sum_d q[n,d]*k[m,d] -> f32 (attn region)
__global__ __launch_bounds__(256) void k_scores(const short* __restrict__ qb,
                                                const short* __restrict__ kb,
                                                float* __restrict__ qk){
  const int gw = blockIdx.x * 4 + (threadIdx.x >> 6);
  const int lane = threadIdx.x & 63;
  const int mt = gw & 63, nt = (gw >> 6) & 63, bh = gw >> 12;
  const int lo = lane & 15, quad = lane >> 4;
  const short* qrow = qb + ((size_t)bh*N_ + nt*16 + lo)*D_ + quad*8;
  const short* krow = kb + ((size_t)bh*N_ + mt*16 + lo)*D_ + quad*8;
  short8 a0 = *(const short8*)qrow;
  short8 b0 = *(const short8*)krow;
  short8 a1 = *(const short8*)(qrow + 32);
  short8 b1 = *(const short8*)(krow + 32);
  f32x4 acc = {0.f, 0.f, 0.f, 0.f};
  acc = __builtin_amdgcn_mfma_f32_16x16x32_bf16(a0, b0, acc, 0, 0, 0);
  acc = __builtin_amdgcn_mfma_f32_16x16x32_bf16(a1, b1, acc, 0, 0, 0);
  float* o = qk + (size_t)bh*N_*N_ + (size_t)(nt*16)*N_ + mt*16;
  #pragma unroll
  for (int r = 0; r < 4; r++)
    o[(size_t)(quad*4 + r)*N_ + lo] = acc[r];   // row=(lane>>4)*4+reg, col=lane&15
}

// ---------------- Kernel D (merged stats+softmax+conv+tanh+gumbel):
// one block per (b,n) row; handles all H=6 heads x 1024 m.
// NOTE: R1 structure restored verbatim — the R2 conv-hoist/exp-reuse variant kept
// qv[24]+up[24] live across the whole body and added ~28 us of issue stalls
// (VALUBusy 90%->74% at identical VALU-cycle count). Issue-bound kernel: keep
// live ranges short; recomputing exp is cheaper than holding it.
__global__ __launch_bounds__(256) void k_fuse(float* __restrict__ attn,    // in: scores, out: attn_mean
                                              const float* __restrict__ cw,
                                              const float* __restrict__ cb,
                                              float* __restrict__ u_out,
                                              unsigned long long* __restrict__ mbits,
                                              uint32_t g0k0, uint32_t g0k1,
                                              uint32_t g1k0, uint32_t g1k1){
  const int bn = blockIdx.x;                  // 0..4095
  const int bb = bn >> 10, n = bn & 1023;
  const int t = threadIdx.x, lane = t & 63, wid = t >> 6;
  __shared__ float redm[H_][4], reds[H_][4];

  float qv[H_][4];
  #pragma unroll
  for (int h = 0; h < H_; h++){
    const float* p = attn + (((size_t)(bb*H_ + h) << 10) + n) * N_;
    #pragma unroll
    for (int i = 0; i < 4; i++) qv[h][i] = p[t + 256*i];
  }
  // per-head max (wave shuffle + LDS cross-wave)
  #pragma unroll
  for (int h = 0; h < H_; h++){
    float mx = fmaxf(fmaxf(qv[h][0], qv[h][1]), fmaxf(qv[h][2], qv[h][3]));
    #pragma unroll
    for (int off = 32; off > 0; off >>= 1) mx = fmaxf(mx, __shfl_xor(mx, off));
    if (lane == 0) redm[h][wid] = mx;
  }
  __syncthreads();
  float mxh[H_], sm[H_];
  #pragma unroll
  for (int h = 0; h < H_; h++){
    mxh[h] = fmaxf(fmaxf(redm[h][0], redm[h][1]), fmaxf(redm[h][2], redm[h][3]));
    const float k2 = SCALE * LOG2E;
    float s = 0.f;
    #pragma unroll
    for (int i = 0; i < 4; i++) s += __builtin_amdgcn_exp2f((qv[h][i] - mxh[h]) * k2);
    #pragma unroll
    for (int off = 32; off > 0; off >>= 1) s += __shfl_xor(s, off);
    if (lane == 0) reds[h][wid] = s;
    sm[h] = s;
  }
  __syncthreads();
  float invS[H_];
  #pragma unroll
  for (int h = 0; h < H_; h++){
    float S = reds[h][0] + reds[h][1] + reds[h][2] + reds[h][3];
    invS[h] = __builtin_amdgcn_rcpf(S);
  }
  // write attn_mean (recompute exp)
  #pragma unroll
  for (int h = 0; h < H_; h++){
    float* p = attn + (((size_t)(bb*H_ + h) << 10) + n) * N_;
    const float k2 = SCALE * LOG2E;
    #pragma unroll
    for (int i = 0; i < 4; i++)
      p[t + 256*i] = __builtin_amdgcn_exp2f((qv[h][i] - mxh[h]) * k2) * invS[h];
  }
  // conv mix + u + gumbel hard bits
  // hard = (g1 - g0 > 2u-1). With L_i = log2(f_i) (both < 0) and t = tanh(up):
  //   g1 - g0 = ln(L0/L1)  =>  hard <=> L0 < L1 * e^t   (L1 < 0 flips)
  const uint32_t a2k = g0k0 ^ g0k1 ^ 0x1BD11BDAu;
  const uint32_t b2k = g1k0 ^ g1k1 ^ 0x1BD11BDAu;
  const uint32_t jrow = ((uint32_t)(bb*H_) << 20) | ((uint32_t)n << 10);
  #pragma unroll
  for (int i = 0; i < 4; i++){
    const uint32_t m = (uint32_t)(t + 256*i);
    #pragma unroll
    for (int o = 0; o < H_; o++){
      float up = cb[o];
      #pragma unroll
      for (int h = 0; h < H_; h++) up += cw[o*H_ + h] * qv[h][i];
      // u = (tanh(up)+1)/2 == sigmoid(2*up)
      float eneg = __builtin_amdgcn_exp2f(-2.0f * LOG2E * up);
      float uu   = __builtin_amdgcn_rcpf(1.0f + eneg);
      float tt   = 2.0f * uu - 1.0f;                      // tanh(up)
      float et   = __builtin_amdgcn_exp2f(tt * LOG2E);    // e^t
      uint32_t j = jrow + ((uint32_t)o << 20) + m;
      float f0, f1;
      tf_dual(j, g0k0, g0k1, a2k, g1k0, g1k1, b2k, f0, f1);
      float L0 = __builtin_amdgcn_logf(f0);               // log2(f0) <= 0
      float L1 = __builtin_amdgcn_logf(f1);
      int hard = L0 < L1 * et;
      u_out[(size_t)j] = uu;
      unsigned long long bal = __ballot(hard);
      if (lane == 0) mbits[(size_t)j >> 6] = bal;
    }
  }
}

// ---------------- Kernel E (MFMA): tmp[b,n,h,d] = sum_m (attn*mask)[bh,n,m] * v[bh,m,d]
// 3072 waves total (~3/SIMD) -> latency-bound serial m-loop; unroll 4 deep so the
// compiler batches 4 iterations of loads ahead of the mask/cvt/MFMA work (ILP for TLP).
__global__ __launch_bounds__(256) void k_av(const float* __restrict__ attn,
                                            const unsigned long long* __restrict__ mbits,
                                            const short* __restrict__ vTb,
                                            float* __restrict__ tmp){
  const int gw = blockIdx.x * 4 + (threadIdx.x >> 6);
  const int lane = threadIdx.x & 63;
  const int pr = gw & 1, nt = (gw >> 1) & 63, bh = gw >> 7;
  const int bb = bh / H_, h = bh - bb*H_;
  const int lo = lane & 15, quad = lane >> 4;
  const int row = nt*16 + lo;                       // n
  const float* arow = attn + ((size_t)bh*N_ + row)*N_ + quad*8;
  const unsigned long long* mrow = mbits + (((size_t)bh*N_ + row)*N_ >> 6);
  const short* vrow0 = vTb + ((size_t)bh*D_ + pr*32 + lo)*N_ + quad*8;
  const short* vrow1 = vrow0 + 16*N_;
  f32x4 acc0 = {0.f, 0.f, 0.f, 0.f};
  f32x4 acc1 = {0.f, 0.f, 0.f, 0.f};
  #pragma unroll
  for (int mb = 0; mb < N_; mb += 128){
    // issue all loads for 4 m-steps first (independent; 4-deep vmcnt pipeline)
    f32x4 av0[4], av1[4];
    unsigned long long wb[4];
    short8 b0[4], b1[4];
    #pragma unroll
    for (int s = 0; s < 4; s++){
      int m0 = mb + s*32;
      av0[s] = *(const f32x4*)(arow + m0);
      av1[s] = *(const f32x4*)(arow + m0 + 4);
      wb[s]  = mrow[(m0 + quad*8) >> 6];
      b0[s]  = *(const short8*)(vrow0 + m0);
      b1[s]  = *(const short8*)(vrow1 + m0);
    }
    #pragma unroll
    for (int s = 0; s < 4; s++){
      int m0 = mb + s*32;
      int base = (m0 + quad*8) & 63;
      float vals[8] = {av0[s][0], av0[s][1], av0[s][2], av0[s][3],
                       av1[s][0], av1[s][1], av1[s][2], av1[s][3]};
      short8 a;
      #pragma unroll
      for (int j = 0; j < 8; j++)
        a[j] = f2bs(((wb[s] >> (base + j)) & 1ull) ? vals[j] : 0.0f);
      acc0 = __builtin_amdgcn_mfma_f32_16x16x32_bf16(a, b0[s], acc0, 0, 0, 0);
      acc1 = __builtin_amdgcn_mfma_f32_16x16x32_bf16(a, b1[s], acc1, 0, 0, 0);
    }
  }
  float* o = tmp + ((size_t)(bb*N_) + nt*16)*C_ + h*D_ + pr*32;
  #pragma unroll
  for (int r = 0; r < 4; r++){
    o[(size_t)(quad*4 + r)*C_ + lo]      = acc0[r];
    o[(size_t)(quad*4 + r)*C_ + 16 + lo] = acc1[r];
  }
}

// ---------------- Kernel F: out = tmp @ proj_w + proj_b (f32 out), 32x64 tiles, packed FMA
__global__ __launch_bounds__(256) void k_proj(const float* __restrict__ A,
                                              const float* __restrict__ w,
                                              const float* __restrict__ bias,
                                              float* __restrict__ out){
  __shared__ __align__(16) float As[16][36];   // [k][m] 32 rows
  __shared__ __align__(16) float Bs[16][68];   // [k][n] 64 cols
  const int t = threadIdx.x, tx = t & 15, ty = t >> 4;
  const int m0 = blockIdx.x * 32, n0 = blockIdx.y * 64;
  const int am = t >> 3,        ak = (t & 7) * 2;   // A: f32x2 along k
  const int bn = (t & 15) * 4,  bk = t >> 4;        // B: f32x4 along n
  f32x2 c[2][2] = {};
  for (int k0 = 0; k0 < C_; k0 += 16){
    f32x2 av = *(const f32x2*)&A[(size_t)(m0+am)*C_ + k0 + ak];
    f32x4 bv = *(const f32x4*)&w[(size_t)(k0+bk)*C_ + n0 + bn];
    __syncthreads();
    As[ak+0][am] = av[0]; As[ak+1][am] = av[1];
    *(f32x4*)&Bs[bk][bn] = bv;
    __syncthreads();
    #pragma unroll
    for (int k = 0; k < 16; k++){
      f32x2 a2 = *(const f32x2*)&As[k][ty*2];
      f4u b; b.v4 = *(const f32x4*)&Bs[k][tx*4];
      pk_fma_ll(c[0][0], a2, b.v2[0]); pk_fma_ll(c[0][1], a2, b.v2[1]);
      pk_fma_hh(c[1][0], a2, b.v2[0]); pk_fma_hh(c[1][1], a2, b.v2[1]);
    }
  }
  #pragma unroll
  for (int i = 0; i < 2; i++)
    #pragma unroll
    for (int jp = 0; jp < 2; jp++)
      #pragma unroll
      for (int sub = 0; sub < 2; sub++){
        int jg = n0 + tx*4 + jp*2 + sub;
        out[(size_t)(m0+ty*2+i)*C_ + jg] = c[i][jp][sub] + bias[jg];
      }
}

extern "C" void kernel_launch(void* const* d_in, const int* in_sizes, int n_in,
                              void* d_out, int out_size, void* d_ws, size_t ws_size,
                              hipStream_t stream) {
  const float* x      = (const float*)d_in[0];
  const float* qkv_w  = (const float*)d_in[1];
  const float* qkv_b  = (const float*)d_in[2];
  const float* proj_w = (const float*)d_in[3];
  const float* proj_b = (const float*)d_in[4];
  const float* conv_w = (const float*)d_in[5];
  const float* conv_b = (const float*)d_in[6];

  float* out      = (float*)d_out;                      // B*N*C
  float* attn_out = out + (size_t)B_*N_*C_;             // B*H*N*N (scores then attn)
  float* u_out    = attn_out + (size_t)BHNN_;           // B*H*N*N

  // workspace layout (18.9 MB total; 28.5 MB proven safe)
  char* ws = (char*)d_ws;
  bf16* qb   = (bf16*)ws;                               // 3,145,728 B
  bf16* kb   = (bf16*)(ws + 3145728);                   // 3,145,728 B
  bf16* vTb  = (bf16*)(ws + 6291456);                   // 3,145,728 B
  unsigned long long* mbits = (unsigned long long*)(ws + 9437184); // 3,145,728 B
  float* tmp = (float*)(ws + 12582912);                 // 6,291,456 B

  // derived gumbel keys: fold_in(key(42)=(0,42), 0) and (.., 1)
  uint32_t g0k0, g0k1, g1k0, g1k1;
  { uint32_t a = 0u, b = 0u; tf2x32(0u, 42u, a, b); g0k0 = a; g0k1 = b; }
  { uint32_t a = 0u, b = 1u; tf2x32(0u, 42u, a, b); g1k0 = a; g1k1 = b; }

  dim3 blk(256);
  k_qkv   <<<dim3(64, 18),  blk, 0, stream>>>(x, qkv_w, qkv_b, qb, kb, vTb);
  k_scores<<<dim3(24576),   blk, 0, stream>>>((const short*)qb, (const short*)kb, attn_out);
  k_fuse  <<<dim3(4096),    blk, 0, stream>>>(attn_out, conv_w, conv_b,
                                              u_out, mbits,
                                              g0k0, g0k1, g1k0, g1k1);
  k_av    <<<dim3(768),     blk, 0, stream>>>(attn_out, mbits, (const short*)vTb, tmp);
  k_proj  <<<dim3(128, 6),  blk, 0, stream>>>(tmp, proj_w, proj_b, out);
}

// Round 5
// 450.564 us; speedup vs baseline: 1.0561x; 1.0561x over previous
//
#include <hip/hip_runtime.h>
#include <hip/hip_bf16.h>
#include <stdint.h>
#include <stddef.h>

#define B_ 4
#define N_ 1024
#define C_ 384
#define H_ 6
#define D_ 64
#define TC_ 1152          // 3*C
#define BHNN_ 25165824    // B*H*N*N
#define SCALE 0.125f
#define LOG2E 1.4426950408889634f
#define LN2 0.6931471805599453f

typedef __hip_bfloat16 bf16;
typedef __attribute__((ext_vector_type(2))) float f32x2;
typedef __attribute__((ext_vector_type(4))) float f32x4;
typedef __attribute__((ext_vector_type(8))) short short8;
typedef __attribute__((ext_vector_type(4))) short short4v;

union f4u { f32x4 v4; f32x2 v2[2]; };

__device__ __forceinline__ short f2bs(float x){
  bf16 b = __float2bfloat16(x);
  return *reinterpret_cast<short*>(&b);
}

// packed dual-FMA with src0 broadcast via op_sel (numerically = v_fma_f32 on both halves)
__device__ __forceinline__ void pk_fma_ll(f32x2& c, f32x2 a, f32x2 b){
  asm("v_pk_fma_f32 %0, %1, %2, %0 op_sel:[0,0,0] op_sel_hi:[0,1,1]" : "+v"(c) : "v"(a), "v"(b));
}
__device__ __forceinline__ void pk_fma_hh(f32x2& c, f32x2 a, f32x2 b){
  asm("v_pk_fma_f32 %0, %1, %2, %0 op_sel:[1,0,0] op_sel_hi:[1,1,1]" : "+v"(c) : "v"(a), "v"(b));
}

// ---------------- Threefry-2x32 (matches jax._src.prng) ----------------
#define TFR(x0,x1,r) { x0 += x1; x1 = ((x1)<<(r))|((x1)>>(32-(r))); x1 ^= x0; }

__host__ __device__ __forceinline__ void tf2x32(uint32_t k0, uint32_t k1,
                                                uint32_t& x0, uint32_t& x1){
  uint32_t k2 = k0 ^ k1 ^ 0x1BD11BDAu;
  x0 += k0; x1 += k1;
  TFR(x0,x1,13) TFR(x0,x1,15) TFR(x0,x1,26) TFR(x0,x1,6)
  x0 += k1; x1 += k2 + 1u;
  TFR(x0,x1,17) TFR(x0,x1,29) TFR(x0,x1,16) TFR(x0,x1,24)
  x0 += k2; x1 += k0 + 2u;
  TFR(x0,x1,13) TFR(x0,x1,15) TFR(x0,x1,26) TFR(x0,x1,6)
  x0 += k0; x1 += k1 + 3u;
  TFR(x0,x1,17) TFR(x0,x1,29) TFR(x0,x1,16) TFR(x0,x1,24)
  x0 += k1; x1 += k2 + 4u;
  TFR(x0,x1,13) TFR(x0,x1,15) TFR(x0,x1,26) TFR(x0,x1,6)
  x0 += k2; x1 += k0 + 5u;
}

__device__ __forceinline__ uint32_t rotl32(uint32_t x, uint32_t r){
#if __has_builtin(__builtin_amdgcn_alignbit)
  return __builtin_amdgcn_alignbit(x, x, 32u - r);
#else
  return (x << r) | (x >> (32u - r));
#endif
}

// dual-stream threefry: uniforms for BOTH gumbel keys at counter (0, j), 2-way ILP
__device__ __forceinline__ void tf_dual(uint32_t j,
    uint32_t ak0, uint32_t ak1, uint32_t ak2,
    uint32_t bk0, uint32_t bk1, uint32_t bk2,
    float& fA, float& fB){
  uint32_t x0 = ak0, x1 = j + ak1;
  uint32_t y0 = bk0, y1 = j + bk1;
  #define DTFR(r) { x0 += x1; y0 += y1;               \
                    x1 = rotl32(x1,(r)); y1 = rotl32(y1,(r)); \
                    x1 ^= x0; y1 ^= y0; }
  DTFR(13) DTFR(15) DTFR(26) DTFR(6)
  x0 += ak1; x1 += ak2 + 1u;  y0 += bk1; y1 += bk2 + 1u;
  DTFR(17) DTFR(29) DTFR(16) DTFR(24)
  x0 += ak2; x1 += ak0 + 2u;  y0 += bk2; y1 += bk0 + 2u;
  DTFR(13) DTFR(15) DTFR(26) DTFR(6)
  x0 += ak0; x1 += ak1 + 3u;  y0 += bk0; y1 += bk1 + 3u;
  DTFR(17) DTFR(29) DTFR(16) DTFR(24)
  x0 += ak1; x1 += ak2 + 4u;  y0 += bk1; y1 += bk2 + 4u;
  DTFR(13) DTFR(15) DTFR(26) DTFR(6)
  x0 += ak2; x1 += ak0 + 5u;  y0 += bk2; y1 += bk0 + 5u;
  #undef DTFR
  uint32_t bitsA = x0 ^ x1;
  uint32_t bitsB = y0 ^ y1;
  fA = fmaxf(__uint_as_float((bitsA >> 9) | 0x3F800000u) - 1.0f, 1.1754943508222875e-38f);
  fB = fmaxf(__uint_as_float((bitsB >> 9) | 0x3F800000u) - 1.0f, 1.1754943508222875e-38f);
}

// ---------------- Kernel P (prep): split x -> bf16 hi/lo; transpose+split qkv_w -> wT hi/lo
// blocks 0..431: w transpose (12 k-tiles x 36 n-tiles of 32x32); blocks 432..623: x split.
__global__ __launch_bounds__(256) void k_prep(const float* __restrict__ x,
                                              const float* __restrict__ w,
                                              short* __restrict__ xhi, short* __restrict__ xlo,
                                              short* __restrict__ wThi, short* __restrict__ wTlo){
  const int t = threadIdx.x;
  if (blockIdx.x < 432){
    const int kt = blockIdx.x % 12, nt = blockIdx.x / 12;
    __shared__ float T[32][33];
    const int col = t & 31, row8 = t >> 5;
    #pragma unroll
    for (int i = 0; i < 4; i++)
      T[row8 + i*8][col] = w[(size_t)(kt*32 + row8 + i*8)*TC_ + nt*32 + col];
    __syncthreads();
    #pragma unroll
    for (int i = 0; i < 4; i++){
      int n = nt*32 + row8 + i*8;
      int k = kt*32 + col;
      float v = T[col][row8 + i*8];          // = w[k][n]
      bf16 hb = __float2bfloat16(v);
      float hf = __bfloat162float(hb);
      bf16 lb = __float2bfloat16(v - hf);
      wThi[(size_t)n*C_ + k] = *(short*)&hb;
      wTlo[(size_t)n*C_ + k] = *(short*)&lb;
    }
  } else {
    // x split: 1,572,864 f32 over 192 blocks x 256 thr x 8 iters x f32x4
    const int b2 = blockIdx.x - 432;
    size_t base = ((size_t)b2*256 + t) * 4;
    #pragma unroll
    for (int it = 0; it < 8; it++){
      size_t idx = base + (size_t)it * 196608;    // 192*256*4
      f32x4 v = *(const f32x4*)&x[idx];
      short4v hs, ls;
      #pragma unroll
      for (int jj = 0; jj < 4; jj++){
        bf16 hb = __float2bfloat16(v[jj]);
        float hf = __bfloat162float(hb);
        bf16 lb = __float2bfloat16(v[jj] - hf);
        hs[jj] = *(short*)&hb; ls[jj] = *(short*)&lb;
      }
      *(short4v*)&xhi[idx] = hs;
      *(short4v*)&xlo[idx] = ls;
    }
  }
}

// ---------------- Kernel A (MFMA, bf16x2): qkv = x @ qkv_w + b
// f32-accurate via 3-term split: ahi*bhi + ahi*blo + alo*bhi (error ~2^-17 rel,
// far below the bf16 rounding applied to qb/kb/vTb anyway).
// 64x64 tile, BK=32, 4 waves; all LDS writes/reads are contiguous-1KB lane
// permutations -> conflict-free. Replaces the LDS-BW-bound f32 version (~67us model).
__global__ __launch_bounds__(256) void k_qkv(const short* __restrict__ xhi,
                                             const short* __restrict__ xlo,
                                             const short* __restrict__ wThi,
                                             const short* __restrict__ wTlo,
                                             const float* __restrict__ bias,
                                             bf16* __restrict__ qb,
                                             bf16* __restrict__ kb,
                                             bf16* __restrict__ vTb){
  __shared__ __align__(16) short sA[2][64][32];   // [hi/lo][m][k]
  __shared__ __align__(16) short sB[2][64][32];   // [hi/lo][n][k]
  const int t = threadIdx.x, lane = t & 63, wv = t >> 6;
  const int lo = lane & 15, quad = lane >> 4;
  const int m0 = blockIdx.x * 64, n0 = blockIdx.y * 64;
  // staging: lane l -> row r=l>>2 (16 rows per wave slice), kq=l&3 (8 shorts each)
  const int sr = lane >> 2, skq = lane & 3;
  const short* srcAh = xhi  + (size_t)(m0 + wv*16 + sr)*C_ + skq*8;
  const short* srcAl = xlo  + (size_t)(m0 + wv*16 + sr)*C_ + skq*8;
  const short* srcBh = wThi + (size_t)(n0 + wv*16 + sr)*C_ + skq*8;
  const short* srcBl = wTlo + (size_t)(n0 + wv*16 + sr)*C_ + skq*8;
  short* dAh = &sA[0][wv*16 + sr][skq*8];   // byte off = wv*1024 + lane*16 (linear)
  short* dAl = &sA[1][wv*16 + sr][skq*8];
  short* dBh = &sB[0][wv*16 + sr][skq*8];
  short* dBl = &sB[1][wv*16 + sr][skq*8];

  f32x4 acc[4] = {{0,0,0,0},{0,0,0,0},{0,0,0,0},{0,0,0,0}};
  for (int k0 = 0; k0 < C_; k0 += 32){
    short8 ra = *(const short8*)(srcAh + k0);
    short8 rb = *(const short8*)(srcAl + k0);
    short8 rc = *(const short8*)(srcBh + k0);
    short8 rd = *(const short8*)(srcBl + k0);
    __syncthreads();                       // prev chunk's readers done
    *(short8*)dAh = ra; *(short8*)dAl = rb;
    *(short8*)dBh = rc; *(short8*)dBl = rd;
    __syncthreads();                       // staged data visible
    short8 ah = *(const short8*)&sA[0][wv*16 + lo][quad*8];
    short8 al = *(const short8*)&sA[1][wv*16 + lo][quad*8];
    #pragma unroll
    for (int j = 0; j < 4; j++){
      short8 bh = *(const short8*)&sB[0][j*16 + lo][quad*8];
      short8 bl = *(const short8*)&sB[1][j*16 + lo][quad*8];
      acc[j] = __builtin_amdgcn_mfma_f32_16x16x32_bf16(ah, bh, acc[j], 0, 0, 0);
      acc[j] = __builtin_amdgcn_mfma_f32_16x16x32_bf16(ah, bl, acc[j], 0, 0, 0);
      acc[j] = __builtin_amdgcn_mfma_f32_16x16x32_bf16(al, bh, acc[j], 0, 0, 0);
    }
  }
  // epilogue: D[row=quad*4+r][col=lo] per 16x16 tile (proven layout from k_scores)
  #pragma unroll
  for (int j = 0; j < 4; j++){
    int ng = n0 + j*16 + lo;
    int t3 = ng / C_;
    int rem = ng - t3*C_;
    int hh = rem >> 6, dd = rem & 63;
    float bsv = bias[ng];
    #pragma unroll
    for (int r = 0; r < 4; r++){
      int mg = m0 + wv*16 + quad*4 + r;
      int bb = mg >> 10, nn = mg & 1023;
      bf16 val = __float2bfloat16(acc[j][r] + bsv);
      if (t3 == 0)      qb[((size_t)(bb*H_ + hh)*N_ + nn)*D_ + dd] = val;
      else if (t3 == 1) kb[((size_t)(bb*H_ + hh)*N_ + nn)*D_ + dd] = val;
      else              vTb[((size_t)(bb*H_ + hh)*D_ + dd)*N_ + nn] = val;
    }
  }
}

// ---------------- Kernel B (MFMA): scores[bh][n][m] = sum_d q[n,d]*k[m,d] -> f32 (attn region)
__global__ __launch_bounds__(256) void k_scores(const short* __restrict__ qb,
                                                const short* __restrict__ kb,
                                                float* __restrict__ qk){
  const int gw = blockIdx.x * 4 + (threadIdx.x >> 6);
  const int lane = threadIdx.x & 63;
  const int mt = gw & 63, nt = (gw >> 6) & 63, bh = gw >> 12;
  const int lo = lane & 15, quad = lane >> 4;
  const short* qrow = qb + ((size_t)bh*N_ + nt*16 + lo)*D_ + quad*8;
  const short* krow = kb + ((size_t)bh*N_ + mt*16 + lo)*D_ + quad*8;
  short8 a0 = *(const short8*)qrow;
  short8 b0 = *(const short8*)krow;
  short8 a1 = *(const short8*)(qrow + 32);
  short8 b1 = *(const short8*)(krow + 32);
  f32x4 acc = {0.f, 0.f, 0.f, 0.f};
  acc = __builtin_amdgcn_mfma_f32_16x16x32_bf16(a0, b0, acc, 0, 0, 0);
  acc = __builtin_amdgcn_mfma_f32_16x16x32_bf16(a1, b1, acc, 0, 0, 0);
  float* o = qk + (size_t)bh*N_*N_ + (size_t)(nt*16)*N_ + mt*16;
  #pragma unroll
  for (int r = 0; r < 4; r++)
    o[(size_t)(quad*4 + r)*N_ + lo] = acc[r];   // row=(lane>>4)*4+reg, col=lane&15
}

// ---------------- Kernel D (merged stats+softmax+conv+tanh+gumbel):
// one block per (b,n) row; handles all H=6 heads x 1024 m.
// R1 structure kept verbatim (131us, 90% VALUBusy, 40 VGPR). Do NOT hoist/batch:
// extending live ranges here costs ~28us of issue stalls (R2 lesson).
__global__ __launch_bounds__(256) void k_fuse(float* __restrict__ attn,    // in: scores, out: attn_mean
                                              const float* __restrict__ cw,
                                              const float* __restrict__ cb,
                                              float* __restrict__ u_out,
                                              unsigned long long* __restrict__ mbits,
                                              uint32_t g0k0, uint32_t g0k1,
                                              uint32_t g1k0, uint32_t g1k1){
  const int bn = blockIdx.x;                  // 0..4095
  const int bb = bn >> 10, n = bn & 1023;
  const int t = threadIdx.x, lane = t & 63, wid = t >> 6;
  __shared__ float redm[H_][4], reds[H_][4];

  float qv[H_][4];
  #pragma unroll
  for (int h = 0; h < H_; h++){
    const float* p = attn + (((size_t)(bb*H_ + h) << 10) + n) * N_;
    #pragma unroll
    for (int i = 0; i < 4; i++) qv[h][i] = p[t + 256*i];
  }
  // per-head max (wave shuffle + LDS cross-wave)
  #pragma unroll
  for (int h = 0; h < H_; h++){
    float mx = fmaxf(fmaxf(qv[h][0], qv[h][1]), fmaxf(qv[h][2], qv[h][3]));
    #pragma unroll
    for (int off = 32; off > 0; off >>= 1) mx = fmaxf(mx, __shfl_xor(mx, off));
    if (lane == 0) redm[h][wid] = mx;
  }
  __syncthreads();
  float mxh[H_], sm[H_];
  #pragma unroll
  for (int h = 0; h < H_; h++){
    mxh[h] = fmaxf(fmaxf(redm[h][0], redm[h][1]), fmaxf(redm[h][2], redm[h][3]));
    const float k2 = SCALE * LOG2E;
    float s = 0.f;
    #pragma unroll
    for (int i = 0; i < 4; i++) s += __builtin_amdgcn_exp2f((qv[h][i] - mxh[h]) * k2);
    #pragma unroll
    for (int off = 32; off > 0; off >>= 1) s += __shfl_xor(s, off);
    if (lane == 0) reds[h][wid] = s;
    sm[h] = s;
  }
  __syncthreads();
  float invS[H_];
  #pragma unroll
  for (int h = 0; h < H_; h++){
    float S = reds[h][0] + reds[h][1] + reds[h][2] + reds[h][3];
    invS[h] = __builtin_amdgcn_rcpf(S);
  }
  // write attn_mean (recompute exp)
  #pragma unroll
  for (int h = 0; h < H_; h++){
    float* p = attn + (((size_t)(bb*H_ + h) << 10) + n) * N_;
    const float k2 = SCALE * LOG2E;
    #pragma unroll
    for (int i = 0; i < 4; i++)
      p[t + 256*i] = __builtin_amdgcn_exp2f((qv[h][i] - mxh[h]) * k2) * invS[h];
  }
  // conv mix + u + gumbel hard bits
  // hard = (g1 - g0 > 2u-1). With L_i = log2(f_i) (both < 0) and t = tanh(up):
  //   g1 - g0 = ln(L0/L1)  =>  hard <=> L0 < L1 * e^t   (L1 < 0 flips)
  const uint32_t a2k = g0k0 ^ g0k1 ^ 0x1BD11BDAu;
  const uint32_t b2k = g1k0 ^ g1k1 ^ 0x1BD11BDAu;
  const uint32_t jrow = ((uint32_t)(bb*H_) << 20) | ((uint32_t)n << 10);
  #pragma unroll
  for (int i = 0; i < 4; i++){
    const uint32_t m = (uint32_t)(t + 256*i);
    #pragma unroll
    for (int o = 0; o < H_; o++){
      float up = cb[o];
      #pragma unroll
      for (int h = 0; h < H_; h++) up += cw[o*H_ + h] * qv[h][i];
      // u = (tanh(up)+1)/2 == sigmoid(2*up)
      float eneg = __builtin_amdgcn_exp2f(-2.0f * LOG2E * up);
      float uu   = __builtin_amdgcn_rcpf(1.0f + eneg);
      float tt   = 2.0f * uu - 1.0f;                      // tanh(up)
      float et   = __builtin_amdgcn_exp2f(tt * LOG2E);    // e^t
      uint32_t j = jrow + ((uint32_t)o << 20) + m;
      float f0, f1;
      tf_dual(j, g0k0, g0k1, a2k, g1k0, g1k1, b2k, f0, f1);
      float L0 = __builtin_amdgcn_logf(f0);               // log2(f0) <= 0
      float L1 = __builtin_amdgcn_logf(f1);
      int hard = L0 < L1 * et;
      u_out[(size_t)j] = uu;
      unsigned long long bal = __ballot(hard);
      if (lane == 0) mbits[(size_t)j >> 6] = bal;
    }
  }
}

// ---------------- Kernel E (MFMA): tmp[b,n,h,d] = sum_m (attn*mask)[bh,n,m] * v[bh,m,d]
// ROLLED loop restored (R3 lesson: unroll-4 load batching cost ~38us — the
// compiler's one-iteration lookahead in the rolled form schedules better).
__global__ __launch_bounds__(256) void k_av(const float* __restrict__ attn,
                                            const unsigned long long* __restrict__ mbits,
                                            const short* __restrict__ vTb,
                                            float* __restrict__ tmp){
  const int gw = blockIdx.x * 4 + (threadIdx.x >> 6);
  const int lane = threadIdx.x & 63;
  const int pr = gw & 1, nt = (gw >> 1) & 63, bh = gw >> 7;
  const int bb = bh / H_, h = bh - bb*H_;
  const int lo = lane & 15, quad = lane >> 4;
  const int row = nt*16 + lo;                       // n
  const float* arow = attn + ((size_t)bh*N_ + row)*N_ + quad*8;
  const unsigned long long* mrow = mbits + (((size_t)bh*N_ + row)*N_ >> 6);
  const short* vrow0 = vTb + ((size_t)bh*D_ + pr*32 + lo)*N_ + quad*8;
  const short* vrow1 = vrow0 + 16*N_;
  f32x4 acc0 = {0.f, 0.f, 0.f, 0.f};
  f32x4 acc1 = {0.f, 0.f, 0.f, 0.f};
  for (int m0 = 0; m0 < N_; m0 += 32){
    f32x4 av0 = *(const f32x4*)(arow + m0);
    f32x4 av1 = *(const f32x4*)(arow + m0 + 4);
    unsigned long long wb = mrow[(m0 + quad*8) >> 6];
    int base = (m0 + quad*8) & 63;
    float vals[8] = {av0[0], av0[1], av0[2], av0[3], av1[0], av1[1], av1[2], av1[3]};
    short8 a;
    #pragma unroll
    for (int j = 0; j < 8; j++)
      a[j] = f2bs(((wb >> (base + j)) & 1ull) ? vals[j] : 0.0f);
    short8 b0 = *(const short8*)(vrow0 + m0);
    short8 b1 = *(const short8*)(vrow1 + m0);
    acc0 = __builtin_amdgcn_mfma_f32_16x16x32_bf16(a, b0, acc0, 0, 0, 0);
    acc1 = __builtin_amdgcn_mfma_f32_16x16x32_bf16(a, b1, acc1, 0, 0, 0);
  }
  float* o = tmp + ((size_t)(bb*N_) + nt*16)*C_ + h*D_ + pr*32;
  #pragma unroll
  for (int r = 0; r < 4; r++){
    o[(size_t)(quad*4 + r)*C_ + lo]      = acc0[r];
    o[(size_t)(quad*4 + r)*C_ + 16 + lo] = acc1[r];
  }
}

// ---------------- Kernel F: out = tmp @ proj_w + proj_b (f32 out), 32x64 tiles, packed FMA
__global__ __launch_bounds__(256) void k_proj(const float* __restrict__ A,
                                              const float* __restrict__ w,
                                              const float* __restrict__ bias,
                                              float* __restrict__ out){
  __shared__ __align__(16) float As[16][36];   // [k][m] 32 rows
  __shared__ __align__(16) float Bs[16][68];   // [k][n] 64 cols
  const int t = threadIdx.x, tx = t & 15, ty = t >> 4;
  const int m0 = blockIdx.x * 32, n0 = blockIdx.y * 64;
  const int am = t >> 3,        ak = (t & 7) * 2;   // A: f32x2 along k
  const int bn = (t & 15) * 4,  bk = t >> 4;        // B: f32x4 along n
  f32x2 c[2][2] = {};
  for (int k0 = 0; k0 < C_; k0 += 16){
    f32x2 av = *(const f32x2*)&A[(size_t)(m0+am)*C_ + k0 + ak];
    f32x4 bv = *(const f32x4*)&w[(size_t)(k0+bk)*C_ + n0 + bn];
    __syncthreads();
    As[ak+0][am] = av[0]; As[ak+1][am] = av[1];
    *(f32x4*)&Bs[bk][bn] = bv;
    __syncthreads();
    #pragma unroll
    for (int k = 0; k < 16; k++){
      f32x2 a2 = *(const f32x2*)&As[k][ty*2];
      f4u b; b.v4 = *(const f32x4*)&Bs[k][tx*4];
      pk_fma_ll(c[0][0], a2, b.v2[0]); pk_fma_ll(c[0][1], a2, b.v2[1]);
      pk_fma_hh(c[1][0], a2, b.v2[0]); pk_fma_hh(c[1][1], a2, b.v2[1]);
    }
  }
  #pragma unroll
  for (int i = 0; i < 2; i++)
    #pragma unroll
    for (int jp = 0; jp < 2; jp++)
      #pragma unroll
      for (int sub = 0; sub < 2; sub++){
        int jg = n0 + tx*4 + jp*2 + sub;
        out[(size_t)(m0+ty*2+i)*C_ + jg] = c[i][jp][sub] + bias[jg];
      }
}

extern "C" void kernel_launch(void* const* d_in, const int* in_sizes, int n_in,
                              void* d_out, int out_size, void* d_ws, size_t ws_size,
                              hipStream_t stream) {
  const float* x      = (const float*)d_in[0];
  const float* qkv_w  = (const float*)d_in[1];
  const float* qkv_b  = (const float*)d_in[2];
  const float* proj_w = (const float*)d_in[3];
  const float* proj_b = (const float*)d_in[4];
  const float* conv_w = (const float*)d_in[5];
  const float* conv_b = (const float*)d_in[6];

  float* out      = (float*)d_out;                      // B*N*C
  float* attn_out = out + (size_t)B_*N_*C_;             // B*H*N*N (scores then attn)
  float* u_out    = attn_out + (size_t)BHNN_;           // B*H*N*N

  // workspace layout (25.7 MB total; 28.5 MB proven safe)
  char* ws = (char*)d_ws;
  bf16*  qb    = (bf16*)ws;                             //  3,145,728 B
  bf16*  kb    = (bf16*)(ws + 3145728);                 //  3,145,728 B
  bf16*  vTb   = (bf16*)(ws + 6291456);                 //  3,145,728 B
  unsigned long long* mbits = (unsigned long long*)(ws + 9437184); // 3,145,728 B
  float* tmp   = (float*)(ws + 12582912);               //  6,291,456 B
  short* xhi   = (short*)(ws + 18874368);               //  3,145,728 B
  short* xlo   = (short*)(ws + 22020096);               //  3,145,728 B
  short* wThi  = (short*)(ws + 25165824);               //    884,736 B
  short* wTlo  = (short*)(ws + 26050560);               //    884,736 B  (end 26,935,296)

  // derived gumbel keys: fold_in(key(42)=(0,42), 0) and (.., 1)
  uint32_t g0k0, g0k1, g1k0, g1k1;
  { uint32_t a = 0u, b = 0u; tf2x32(0u, 42u, a, b); g0k0 = a; g0k1 = b; }
  { uint32_t a = 0u, b = 1u; tf2x32(0u, 42u, a, b); g1k0 = a; g1k1 = b; }

  dim3 blk(256);
  k_prep  <<<dim3(624),     blk, 0, stream>>>(x, qkv_w, xhi, xlo, wThi, wTlo);
  k_qkv   <<<dim3(64, 18),  blk, 0, stream>>>(xhi, xlo, wThi, wTlo, qkv_b, qb, kb, vTb);
  k_scores<<<dim3(24576),   blk, 0, stream>>>((const short*)qb, (const short*)kb, attn_out);
  k_fuse  <<<dim3(4096),    blk, 0, stream>>>(attn_out, conv_w, conv_b,
                                              u_out, mbits,
                                              g0k0, g0k1, g1k0, g1k1);
  k_av    <<<dim3(768),     blk, 0, stream>>>(attn_out, mbits, (const short*)vTb, tmp);
  k_proj  <<<dim3(128, 6),  blk, 0, stream>>>(tmp, proj_w, proj_b, out);
}

// Round 6
// 436.053 us; speedup vs baseline: 1.0912x; 1.0333x over previous
//
#include <hip/hip_runtime.h>
#include <hip/hip_bf16.h>
#include <stdint.h>
#include <stddef.h>

#define B_ 4
#define N_ 1024
#define C_ 384
#define H_ 6
#define D_ 64
#define TC_ 1152          // 3*C
#define BHNN_ 25165824    // B*H*N*N
#define SCALE 0.125f
#define LOG2E 1.4426950408889634f
#define LN2 0.6931471805599453f

typedef __hip_bfloat16 bf16;
typedef __attribute__((ext_vector_type(2))) float f32x2;
typedef __attribute__((ext_vector_type(4))) float f32x4;
typedef __attribute__((ext_vector_type(8))) short short8;
typedef __attribute__((ext_vector_type(4))) short short4v;

union f4u { f32x4 v4; f32x2 v2[2]; };

__device__ __forceinline__ short f2bs(float x){
  bf16 b = __float2bfloat16(x);
  return *reinterpret_cast<short*>(&b);
}

// packed dual-FMA with src0 broadcast via op_sel (numerically = v_fma_f32 on both halves)
__device__ __forceinline__ void pk_fma_ll(f32x2& c, f32x2 a, f32x2 b){
  asm("v_pk_fma_f32 %0, %1, %2, %0 op_sel:[0,0,0] op_sel_hi:[0,1,1]" : "+v"(c) : "v"(a), "v"(b));
}
__device__ __forceinline__ void pk_fma_hh(f32x2& c, f32x2 a, f32x2 b){
  asm("v_pk_fma_f32 %0, %1, %2, %0 op_sel:[1,0,0] op_sel_hi:[1,1,1]" : "+v"(c) : "v"(a), "v"(b));
}

// ---------------- Threefry-2x32 (matches jax._src.prng) ----------------
#define TFR(x0,x1,r) { x0 += x1; x1 = ((x1)<<(r))|((x1)>>(32-(r))); x1 ^= x0; }

__host__ __device__ __forceinline__ void tf2x32(uint32_t k0, uint32_t k1,
                                                uint32_t& x0, uint32_t& x1){
  uint32_t k2 = k0 ^ k1 ^ 0x1BD11BDAu;
  x0 += k0; x1 += k1;
  TFR(x0,x1,13) TFR(x0,x1,15) TFR(x0,x1,26) TFR(x0,x1,6)
  x0 += k1; x1 += k2 + 1u;
  TFR(x0,x1,17) TFR(x0,x1,29) TFR(x0,x1,16) TFR(x0,x1,24)
  x0 += k2; x1 += k0 + 2u;
  TFR(x0,x1,13) TFR(x0,x1,15) TFR(x0,x1,26) TFR(x0,x1,6)
  x0 += k0; x1 += k1 + 3u;
  TFR(x0,x1,17) TFR(x0,x1,29) TFR(x0,x1,16) TFR(x0,x1,24)
  x0 += k1; x1 += k2 + 4u;
  TFR(x0,x1,13) TFR(x0,x1,15) TFR(x0,x1,26) TFR(x0,x1,6)
  x0 += k2; x1 += k0 + 5u;
}

__device__ __forceinline__ uint32_t rotl32(uint32_t x, uint32_t r){
#if __has_builtin(__builtin_amdgcn_alignbit)
  return __builtin_amdgcn_alignbit(x, x, 32u - r);
#else
  return (x << r) | (x >> (32u - r));
#endif
}

// dual-stream threefry: uniforms for BOTH gumbel keys at counter (0, j), 2-way ILP
__device__ __forceinline__ void tf_dual(uint32_t j,
    uint32_t ak0, uint32_t ak1, uint32_t ak2,
    uint32_t bk0, uint32_t bk1, uint32_t bk2,
    float& fA, float& fB){
  uint32_t x0 = ak0, x1 = j + ak1;
  uint32_t y0 = bk0, y1 = j + bk1;
  #define DTFR(r) { x0 += x1; y0 += y1;               \
                    x1 = rotl32(x1,(r)); y1 = rotl32(y1,(r)); \
                    x1 ^= x0; y1 ^= y0; }
  DTFR(13) DTFR(15) DTFR(26) DTFR(6)
  x0 += ak1; x1 += ak2 + 1u;  y0 += bk1; y1 += bk2 + 1u;
  DTFR(17) DTFR(29) DTFR(16) DTFR(24)
  x0 += ak2; x1 += ak0 + 2u;  y0 += bk2; y1 += bk0 + 2u;
  DTFR(13) DTFR(15) DTFR(26) DTFR(6)
  x0 += ak0; x1 += ak1 + 3u;  y0 += bk0; y1 += bk1 + 3u;
  DTFR(17) DTFR(29) DTFR(16) DTFR(24)
  x0 += ak1; x1 += ak2 + 4u;  y0 += bk1; y1 += bk2 + 4u;
  DTFR(13) DTFR(15) DTFR(26) DTFR(6)
  x0 += ak2; x1 += ak0 + 5u;  y0 += bk2; y1 += bk0 + 5u;
  #undef DTFR
  uint32_t bitsA = x0 ^ x1;
  uint32_t bitsB = y0 ^ y1;
  fA = fmaxf(__uint_as_float((bitsA >> 9) | 0x3F800000u) - 1.0f, 1.1754943508222875e-38f);
  fB = fmaxf(__uint_as_float((bitsB >> 9) | 0x3F800000u) - 1.0f, 1.1754943508222875e-38f);
}

// ---------------- Kernel P (prep): split x -> bf16 hi/lo; transpose+split qkv_w -> wT hi/lo
// blocks 0..431: w transpose (12 k-tiles x 36 n-tiles of 32x32); blocks 432..623: x split.
__global__ __launch_bounds__(256) void k_prep(const float* __restrict__ x,
                                              const float* __restrict__ w,
                                              short* __restrict__ xhi, short* __restrict__ xlo,
                                              short* __restrict__ wThi, short* __restrict__ wTlo){
  const int t = threadIdx.x;
  if (blockIdx.x < 432){
    const int kt = blockIdx.x % 12, nt = blockIdx.x / 12;
    __shared__ float T[32][33];
    const int col = t & 31, row8 = t >> 5;
    #pragma unroll
    for (int i = 0; i < 4; i++)
      T[row8 + i*8][col] = w[(size_t)(kt*32 + row8 + i*8)*TC_ + nt*32 + col];
    __syncthreads();
    #pragma unroll
    for (int i = 0; i < 4; i++){
      int n = nt*32 + row8 + i*8;
      int k = kt*32 + col;
      float v = T[col][row8 + i*8];          // = w[k][n]
      bf16 hb = __float2bfloat16(v);
      float hf = __bfloat162float(hb);
      bf16 lb = __float2bfloat16(v - hf);
      wThi[(size_t)n*C_ + k] = *(short*)&hb;
      wTlo[(size_t)n*C_ + k] = *(short*)&lb;
    }
  } else {
    // x split: 1,572,864 f32 over 192 blocks x 256 thr x 8 iters x f32x4
    const int b2 = blockIdx.x - 432;
    size_t base = ((size_t)b2*256 + t) * 4;
    #pragma unroll
    for (int it = 0; it < 8; it++){
      size_t idx = base + (size_t)it * 196608;    // 192*256*4
      f32x4 v = *(const f32x4*)&x[idx];
      short4v hs, ls;
      #pragma unroll
      for (int jj = 0; jj < 4; jj++){
        bf16 hb = __float2bfloat16(v[jj]);
        float hf = __bfloat162float(hb);
        bf16 lb = __float2bfloat16(v[jj] - hf);
        hs[jj] = *(short*)&hb; ls[jj] = *(short*)&lb;
      }
      *(short4v*)&xhi[idx] = hs;
      *(short4v*)&xlo[idx] = ls;
    }
  }
}

// ---------------- Kernel A (MFMA, bf16x2): qkv = x @ qkv_w + b
// f32-accurate via 3-term split: ahi*bhi + ahi*blo + alo*bhi.
// R6: software-pipelined staging — next K-step's global loads issue right after
// this step's ds_writes, hiding HBM/L2 latency under the barrier + 12 MFMAs
// (T3-minimum pattern). Previously loads were consumed in-iteration (exposed).
__global__ __launch_bounds__(256) void k_qkv(const short* __restrict__ xhi,
                                             const short* __restrict__ xlo,
                                             const short* __restrict__ wThi,
                                             const short* __restrict__ wTlo,
                                             const float* __restrict__ bias,
                                             bf16* __restrict__ qb,
                                             bf16* __restrict__ kb,
                                             bf16* __restrict__ vTb){
  __shared__ __align__(16) short sA[2][64][32];   // [hi/lo][m][k]
  __shared__ __align__(16) short sB[2][64][32];   // [hi/lo][n][k]
  const int t = threadIdx.x, lane = t & 63, wv = t >> 6;
  const int lo = lane & 15, quad = lane >> 4;
  const int m0 = blockIdx.x * 64, n0 = blockIdx.y * 64;
  const int sr = lane >> 2, skq = lane & 3;
  const short* srcAh = xhi  + (size_t)(m0 + wv*16 + sr)*C_ + skq*8;
  const short* srcAl = xlo  + (size_t)(m0 + wv*16 + sr)*C_ + skq*8;
  const short* srcBh = wThi + (size_t)(n0 + wv*16 + sr)*C_ + skq*8;
  const short* srcBl = wTlo + (size_t)(n0 + wv*16 + sr)*C_ + skq*8;
  short* dAh = &sA[0][wv*16 + sr][skq*8];   // byte off = wv*1024 + lane*16 (linear)
  short* dAl = &sA[1][wv*16 + sr][skq*8];
  short* dBh = &sB[0][wv*16 + sr][skq*8];
  short* dBl = &sB[1][wv*16 + sr][skq*8];

  f32x4 acc[4] = {{0,0,0,0},{0,0,0,0},{0,0,0,0},{0,0,0,0}};
  short8 ra = *(const short8*)(srcAh);
  short8 rb = *(const short8*)(srcAl);
  short8 rc = *(const short8*)(srcBh);
  short8 rd = *(const short8*)(srcBl);
  for (int k0 = 0; k0 < C_; k0 += 32){
    __syncthreads();                       // prev chunk's readers done
    *(short8*)dAh = ra; *(short8*)dAl = rb;
    *(short8*)dBh = rc; *(short8*)dBl = rd;
    if (k0 + 32 < C_){                     // prefetch next chunk (uniform branch)
      ra = *(const short8*)(srcAh + k0 + 32);
      rb = *(const short8*)(srcAl + k0 + 32);
      rc = *(const short8*)(srcBh + k0 + 32);
      rd = *(const short8*)(srcBl + k0 + 32);
    }
    __syncthreads();                       // staged data visible
    short8 ah = *(const short8*)&sA[0][wv*16 + lo][quad*8];
    short8 al = *(const short8*)&sA[1][wv*16 + lo][quad*8];
    #pragma unroll
    for (int j = 0; j < 4; j++){
      short8 bh = *(const short8*)&sB[0][j*16 + lo][quad*8];
      short8 bl = *(const short8*)&sB[1][j*16 + lo][quad*8];
      acc[j] = __builtin_amdgcn_mfma_f32_16x16x32_bf16(ah, bh, acc[j], 0, 0, 0);
      acc[j] = __builtin_amdgcn_mfma_f32_16x16x32_bf16(ah, bl, acc[j], 0, 0, 0);
      acc[j] = __builtin_amdgcn_mfma_f32_16x16x32_bf16(al, bh, acc[j], 0, 0, 0);
    }
  }
  // epilogue: D[row=quad*4+r][col=lo] per 16x16 tile
  #pragma unroll
  for (int j = 0; j < 4; j++){
    int ng = n0 + j*16 + lo;
    int t3 = ng / C_;
    int rem = ng - t3*C_;
    int hh = rem >> 6, dd = rem & 63;
    float bsv = bias[ng];
    #pragma unroll
    for (int r = 0; r < 4; r++){
      int mg = m0 + wv*16 + quad*4 + r;
      int bb = mg >> 10, nn = mg & 1023;
      bf16 val = __float2bfloat16(acc[j][r] + bsv);
      if (t3 == 0)      qb[((size_t)(bb*H_ + hh)*N_ + nn)*D_ + dd] = val;
      else if (t3 == 1) kb[((size_t)(bb*H_ + hh)*N_ + nn)*D_ + dd] = val;
      else              vTb[((size_t)(bb*H_ + hh)*D_ + dd)*N_ + nn] = val;
    }
  }
}

// ---------------- Kernel B (MFMA): scores[bh][n][m] = sum_d q[n,d]*k[m,d] -> f32 (attn region)
__global__ __launch_bounds__(256) void k_scores(const short* __restrict__ qb,
                                                const short* __restrict__ kb,
                                                float* __restrict__ qk){
  const int gw = blockIdx.x * 4 + (threadIdx.x >> 6);
  const int lane = threadIdx.x & 63;
  const int mt = gw & 63, nt = (gw >> 6) & 63, bh = gw >> 12;
  const int lo = lane & 15, quad = lane >> 4;
  const short* qrow = qb + ((size_t)bh*N_ + nt*16 + lo)*D_ + quad*8;
  const short* krow = kb + ((size_t)bh*N_ + mt*16 + lo)*D_ + quad*8;
  short8 a0 = *(const short8*)qrow;
  short8 b0 = *(const short8*)krow;
  short8 a1 = *(const short8*)(qrow + 32);
  short8 b1 = *(const short8*)(krow + 32);
  f32x4 acc = {0.f, 0.f, 0.f, 0.f};
  acc = __builtin_amdgcn_mfma_f32_16x16x32_bf16(a0, b0, acc, 0, 0, 0);
  acc = __builtin_amdgcn_mfma_f32_16x16x32_bf16(a1, b1, acc, 0, 0, 0);
  float* o = qk + (size_t)bh*N_*N_ + (size_t)(nt*16)*N_ + mt*16;
  #pragma unroll
  for (int r = 0; r < 4; r++)
    o[(size_t)(quad*4 + r)*N_ + lo] = acc[r];   // row=(lane>>4)*4+reg, col=lane&15
}

// ---------------- Kernel D (merged stats+softmax+conv+tanh+gumbel):
// one block per (b,n) row; handles all H=6 heads x 1024 m.
// R1 structure kept verbatim (131us, 90% VALUBusy, 40 VGPR). Do NOT hoist/batch:
// extending live ranges here costs ~28us of issue stalls (R2 lesson).
__global__ __launch_bounds__(256) void k_fuse(float* __restrict__ attn,    // in: scores, out: attn_mean
                                              const float* __restrict__ cw,
                                              const float* __restrict__ cb,
                                              float* __restrict__ u_out,
                                              unsigned long long* __restrict__ mbits,
                                              uint32_t g0k0, uint32_t g0k1,
                                              uint32_t g1k0, uint32_t g1k1){
  const int bn = blockIdx.x;                  // 0..4095
  const int bb = bn >> 10, n = bn & 1023;
  const int t = threadIdx.x, lane = t & 63, wid = t >> 6;
  __shared__ float redm[H_][4], reds[H_][4];

  float qv[H_][4];
  #pragma unroll
  for (int h = 0; h < H_; h++){
    const float* p = attn + (((size_t)(bb*H_ + h) << 10) + n) * N_;
    #pragma unroll
    for (int i = 0; i < 4; i++) qv[h][i] = p[t + 256*i];
  }
  // per-head max (wave shuffle + LDS cross-wave)
  #pragma unroll
  for (int h = 0; h < H_; h++){
    float mx = fmaxf(fmaxf(qv[h][0], qv[h][1]), fmaxf(qv[h][2], qv[h][3]));
    #pragma unroll
    for (int off = 32; off > 0; off >>= 1) mx = fmaxf(mx, __shfl_xor(mx, off));
    if (lane == 0) redm[h][wid] = mx;
  }
  __syncthreads();
  float mxh[H_], sm[H_];
  #pragma unroll
  for (int h = 0; h < H_; h++){
    mxh[h] = fmaxf(fmaxf(redm[h][0], redm[h][1]), fmaxf(redm[h][2], redm[h][3]));
    const float k2 = SCALE * LOG2E;
    float s = 0.f;
    #pragma unroll
    for (int i = 0; i < 4; i++) s += __builtin_amdgcn_exp2f((qv[h][i] - mxh[h]) * k2);
    #pragma unroll
    for (int off = 32; off > 0; off >>= 1) s += __shfl_xor(s, off);
    if (lane == 0) reds[h][wid] = s;
    sm[h] = s;
  }
  __syncthreads();
  float invS[H_];
  #pragma unroll
  for (int h = 0; h < H_; h++){
    float S = reds[h][0] + reds[h][1] + reds[h][2] + reds[h][3];
    invS[h] = __builtin_amdgcn_rcpf(S);
  }
  // write attn_mean (recompute exp)
  #pragma unroll
  for (int h = 0; h < H_; h++){
    float* p = attn + (((size_t)(bb*H_ + h) << 10) + n) * N_;
    const float k2 = SCALE * LOG2E;
    #pragma unroll
    for (int i = 0; i < 4; i++)
      p[t + 256*i] = __builtin_amdgcn_exp2f((qv[h][i] - mxh[h]) * k2) * invS[h];
  }
  // conv mix + u + gumbel hard bits
  // hard = (g1 - g0 > 2u-1). With L_i = log2(f_i) (both < 0) and t = tanh(up):
  //   g1 - g0 = ln(L0/L1)  =>  hard <=> L0 < L1 * e^t   (L1 < 0 flips)
  const uint32_t a2k = g0k0 ^ g0k1 ^ 0x1BD11BDAu;
  const uint32_t b2k = g1k0 ^ g1k1 ^ 0x1BD11BDAu;
  const uint32_t jrow = ((uint32_t)(bb*H_) << 20) | ((uint32_t)n << 10);
  #pragma unroll
  for (int i = 0; i < 4; i++){
    const uint32_t m = (uint32_t)(t + 256*i);
    #pragma unroll
    for (int o = 0; o < H_; o++){
      float up = cb[o];
      #pragma unroll
      for (int h = 0; h < H_; h++) up += cw[o*H_ + h] * qv[h][i];
      // u = (tanh(up)+1)/2 == sigmoid(2*up)
      float eneg = __builtin_amdgcn_exp2f(-2.0f * LOG2E * up);
      float uu   = __builtin_amdgcn_rcpf(1.0f + eneg);
      float tt   = 2.0f * uu - 1.0f;                      // tanh(up)
      float et   = __builtin_amdgcn_exp2f(tt * LOG2E);    // e^t
      uint32_t j = jrow + ((uint32_t)o << 20) + m;
      float f0, f1;
      tf_dual(j, g0k0, g0k1, a2k, g1k0, g1k1, b2k, f0, f1);
      float L0 = __builtin_amdgcn_logf(f0);               // log2(f0) <= 0
      float L1 = __builtin_amdgcn_logf(f1);
      int hard = L0 < L1 * et;
      u_out[(size_t)j] = uu;
      unsigned long long bal = __ballot(hard);
      if (lane == 0) mbits[(size_t)j >> 6] = bal;
    }
  }
}

// ---------------- Kernel E (MFMA): tmp[b,n,h,d] = sum_m (attn*mask)[bh,n,m] * v[bh,m,d]
// R6 restructure: waves split the M-RANGE (two 512-halves), each covering all 64 d
// (4 accumulators), partials summed via LDS at the end. vs old d-split: attn rows
// read ONCE not twice (halves read traffic) and the serial m-chain is 16 iters
// not 32 (halves exposed latency). Same grid/waves/MFMA count. Rolled loop (R3 lesson).
__global__ __launch_bounds__(256) void k_av(const float* __restrict__ attn,
                                            const unsigned long long* __restrict__ mbits,
                                            const short* __restrict__ vTb,
                                            float* __restrict__ tmp){
  __shared__ __align__(16) float red[2][4][64][4];   // [ntl][dt][lane][4] = 8 KB
  const int w = threadIdx.x >> 6, lane = threadIdx.x & 63;
  const int ntl = w >> 1, mh = w & 1;                // 2 n-tiles/block x 2 m-halves
  const int bh = blockIdx.x >> 5, ntp = blockIdx.x & 31;
  const int nt = ntp*2 + ntl;
  const int bb = bh / H_, h = bh - bb*H_;
  const int lo = lane & 15, quad = lane >> 4;
  const int row = nt*16 + lo;                        // n
  const float* arow = attn + ((size_t)bh*N_ + row)*N_ + quad*8;
  const unsigned long long* mrow = mbits + (((size_t)bh*N_ + row)*N_ >> 6);
  const short* vbase = vTb + ((size_t)bh*D_ + lo)*N_ + quad*8;
  f32x4 acc[4] = {{0,0,0,0},{0,0,0,0},{0,0,0,0},{0,0,0,0}};
  const int mstart = mh * 512;
  for (int m0 = mstart; m0 < mstart + 512; m0 += 32){
    f32x4 av0 = *(const f32x4*)(arow + m0);
    f32x4 av1 = *(const f32x4*)(arow + m0 + 4);
    unsigned long long wb = mrow[(m0 + quad*8) >> 6];
    int base = (m0 + quad*8) & 63;
    float vals[8] = {av0[0], av0[1], av0[2], av0[3], av1[0], av1[1], av1[2], av1[3]};
    short8 a;
    #pragma unroll
    for (int j = 0; j < 8; j++)
      a[j] = f2bs(((wb >> (base + j)) & 1ull) ? vals[j] : 0.0f);
    #pragma unroll
    for (int dt = 0; dt < 4; dt++){
      short8 bv = *(const short8*)(vbase + (size_t)(dt*16)*N_ + m0);
      acc[dt] = __builtin_amdgcn_mfma_f32_16x16x32_bf16(a, bv, acc[dt], 0, 0, 0);
    }
  }
  if (mh == 1){
    #pragma unroll
    for (int dt = 0; dt < 4; dt++)
      *(f32x4*)&red[ntl][dt][lane][0] = acc[dt];
  }
  __syncthreads();
  if (mh == 0){
    float* o = tmp + ((size_t)(bb*N_) + nt*16)*C_ + h*D_;
    #pragma unroll
    for (int dt = 0; dt < 4; dt++){
      f32x4 other = *(const f32x4*)&red[ntl][dt][lane][0];
      f32x4 s = acc[dt] + other;
      #pragma unroll
      for (int r = 0; r < 4; r++)
        o[(size_t)(quad*4 + r)*C_ + dt*16 + lo] = s[r];
    }
  }
}

// ---------------- Kernel F: out = tmp @ proj_w + proj_b (f32 out), 32x64 tiles, packed FMA
__global__ __launch_bounds__(256) void k_proj(const float* __restrict__ A,
                                              const float* __restrict__ w,
                                              const float* __restrict__ bias,
                                              float* __restrict__ out){
  __shared__ __align__(16) float As[16][36];   // [k][m] 32 rows
  __shared__ __align__(16) float Bs[16][68];   // [k][n] 64 cols
  const int t = threadIdx.x, tx = t & 15, ty = t >> 4;
  const int m0 = blockIdx.x * 32, n0 = blockIdx.y * 64;
  const int am = t >> 3,        ak = (t & 7) * 2;   // A: f32x2 along k
  const int bn = (t & 15) * 4,  bk = t >> 4;        // B: f32x4 along n
  f32x2 c[2][2] = {};
  for (int k0 = 0; k0 < C_; k0 += 16){
    f32x2 av = *(const f32x2*)&A[(size_t)(m0+am)*C_ + k0 + ak];
    f32x4 bv = *(const f32x4*)&w[(size_t)(k0+bk)*C_ + n0 + bn];
    __syncthreads();
    As[ak+0][am] = av[0]; As[ak+1][am] = av[1];
    *(f32x4*)&Bs[bk][bn] = bv;
    __syncthreads();
    #pragma unroll
    for (int k = 0; k < 16; k++){
      f32x2 a2 = *(const f32x2*)&As[k][ty*2];
      f4u b; b.v4 = *(const f32x4*)&Bs[k][tx*4];
      pk_fma_ll(c[0][0], a2, b.v2[0]); pk_fma_ll(c[0][1], a2, b.v2[1]);
      pk_fma_hh(c[1][0], a2, b.v2[0]); pk_fma_hh(c[1][1], a2, b.v2[1]);
    }
  }
  #pragma unroll
  for (int i = 0; i < 2; i++)
    #pragma unroll
    for (int jp = 0; jp < 2; jp++)
      #pragma unroll
      for (int sub = 0; sub < 2; sub++){
        int jg = n0 + tx*4 + jp*2 + sub;
        out[(size_t)(m0+ty*2+i)*C_ + jg] = c[i][jp][sub] + bias[jg];
      }
}

extern "C" void kernel_launch(void* const* d_in, const int* in_sizes, int n_in,
                              void* d_out, int out_size, void* d_ws, size_t ws_size,
                              hipStream_t stream) {
  const float* x      = (const float*)d_in[0];
  const float* qkv_w  = (const float*)d_in[1];
  const float* qkv_b  = (const float*)d_in[2];
  const float* proj_w = (const float*)d_in[3];
  const float* proj_b = (const float*)d_in[4];
  const float* conv_w = (const float*)d_in[5];
  const float* conv_b = (const float*)d_in[6];

  float* out      = (float*)d_out;                      // B*N*C
  float* attn_out = out + (size_t)B_*N_*C_;             // B*H*N*N (scores then attn)
  float* u_out    = attn_out + (size_t)BHNN_;           // B*H*N*N

  // workspace layout (25.7 MB total; 28.5 MB proven safe)
  char* ws = (char*)d_ws;
  bf16*  qb    = (bf16*)ws;                             //  3,145,728 B
  bf16*  kb    = (bf16*)(ws + 3145728);                 //  3,145,728 B
  bf16*  vTb   = (bf16*)(ws + 6291456);                 //  3,145,728 B
  unsigned long long* mbits = (unsigned long long*)(ws + 9437184); // 3,145,728 B
  float* tmp   = (float*)(ws + 12582912);               //  6,291,456 B
  short* xhi   = (short*)(ws + 18874368);               //  3,145,728 B
  short* xlo   = (short*)(ws + 22020096);               //  3,145,728 B
  short* wThi  = (short*)(ws + 25165824);               //    884,736 B
  short* wTlo  = (short*)(ws + 26050560);               //    884,736 B  (end 26,935,296)

  // derived gumbel keys: fold_in(key(42)=(0,42), 0) and (.., 1)
  uint32_t g0k0, g0k1, g1k0, g1k1;
  { uint32_t a = 0u, b = 0u; tf2x32(0u, 42u, a, b); g0k0 = a; g0k1 = b; }
  { uint32_t a = 0u, b = 1u; tf2x32(0u, 42u, a, b); g1k0 = a; g1k1 = b; }

  dim3 blk(256);
  k_prep  <<<dim3(624),     blk, 0, stream>>>(x, qkv_w, xhi, xlo, wThi, wTlo);
  k_qkv   <<<dim3(64, 18),  blk, 0, stream>>>(xhi, xlo, wThi, wTlo, qkv_b, qb, kb, vTb);
  k_scores<<<dim3(24576),   blk, 0, stream>>>((const short*)qb, (const short*)kb, attn_out);
  k_fuse  <<<dim3(4096),    blk, 0, stream>>>(attn_out, conv_w, conv_b,
                                              u_out, mbits,
                                              g0k0, g0k1, g1k0, g1k1);
  k_av    <<<dim3(768),     blk, 0, stream>>>(attn_out, mbits, (const short*)vTb, tmp);
  k_proj  <<<dim3(128, 6),  blk, 0, stream>>>(tmp, proj_w, proj_b, out);
}